// Round 1
// baseline (288.366 us; speedup 1.0000x reference)
//
#include <hip/hip_runtime.h>
#include <hip/hip_bf16.h>

// Problem dims (hardcoded): B=4, S=2048, D=768, H=12, hd=64
typedef __bf16 bf16;
typedef __bf16 bf16x8 __attribute__((ext_vector_type(8)));
typedef __bf16 bf16x4 __attribute__((ext_vector_type(4)));
typedef short  s16x4  __attribute__((ext_vector_type(4)));
typedef float  f32x4  __attribute__((ext_vector_type(4)));

#if defined(__has_builtin)
#if __has_builtin(__builtin_amdgcn_mfma_f32_16x16x16bf16_1k)
#define HAVE_MFMA16 1
#endif
#endif

__device__ __forceinline__ void gl_lds16(const void* g, void* l) {
  __builtin_amdgcn_global_load_lds(
      (__attribute__((address_space(1))) const void*)g,
      (__attribute__((address_space(3))) void*)l, 16, 0, 0);
}

__device__ __forceinline__ f32x4 mfma32(bf16x8 a, bf16x8 b, f32x4 c) {
  return __builtin_amdgcn_mfma_f32_16x16x32_bf16(a, b, c, 0, 0, 0);
}
#if HAVE_MFMA16
__device__ __forceinline__ f32x4 mfma16(s16x4 a, s16x4 b, f32x4 c) {
  return __builtin_amdgcn_mfma_f32_16x16x16bf16_1k(a, b, c, 0, 0, 0);
}
#endif

// ---------------- fp32 -> bf16 convert (vectorized) ----------------
__global__ void cvtk(const float* __restrict__ src, bf16* __restrict__ dst, int n4) {
  int i = blockIdx.x * 256 + threadIdx.x;
  if (i < n4) {
    float4 v = ((const float4*)src)[i];
    bf16x4 o;
    o[0] = (bf16)v.x; o[1] = (bf16)v.y; o[2] = (bf16)v.z; o[3] = (bf16)v.w;
    ((bf16x4*)dst)[i] = o;
  }
}

// ---------------- GEMM: C[M][N] = A[M][K] * B[N][K]^T, K=768 -------
// MODE 0: Cout = float*, row-major [M][768]
// MODE 1: Cout = bf16*, scatter to qkv[mat][b][h][s][64] (N=2304)
template <int MODE>
__global__ void gemm_bt(const bf16* __restrict__ A, const bf16* __restrict__ Bm,
                        void* __restrict__ Cout) {
  constexpr int K = 768;
  __shared__ __align__(16) char As[128 * 64]; // 128 rows x 32 bf16, 4 chunks/row, swizzled
  __shared__ __align__(16) char Bs[128 * 64];
  const int tid = threadIdx.x;
  const int w = tid >> 6, lane = tid & 63;
  const int quad = lane >> 4, l15 = lane & 15;
  const int wrow = w >> 1, wcol = w & 1;
  const int m0 = blockIdx.x * 128, n0 = blockIdx.y * 128;

  f32x4 acc[4][4];
#pragma unroll
  for (int mt = 0; mt < 4; ++mt)
#pragma unroll
    for (int nt = 0; nt < 4; ++nt) acc[mt][nt] = (f32x4){0.f, 0.f, 0.f, 0.f};

  for (int k0 = 0; k0 < K; k0 += 32) {
    __syncthreads();
#pragma unroll
    for (int i = 0; i < 2; ++i) {
      int L = i * 256 + tid;          // chunk index 0..511
      int r = L >> 2, cl = L & 3;
      int cg = cl ^ ((r >> 1) & 3);   // swizzle: conflict-free frag reads
      gl_lds16(A + (size_t)(m0 + r) * K + k0 + cg * 8, As + (i * 256 + w * 64) * 16);
      gl_lds16(Bm + (size_t)(n0 + r) * K + k0 + cg * 8, Bs + (i * 256 + w * 64) * 16);
    }
    __syncthreads();

    bf16x8 af[4], bfr[4];
#pragma unroll
    for (int mt = 0; mt < 4; ++mt) {
      int r = wrow * 64 + mt * 16 + l15;
      int cl = quad ^ ((r >> 1) & 3);
      af[mt] = *(const bf16x8*)(As + r * 64 + cl * 16);
    }
#pragma unroll
    for (int nt = 0; nt < 4; ++nt) {
      int r = wcol * 64 + nt * 16 + l15;
      int cl = quad ^ ((r >> 1) & 3);
      bfr[nt] = *(const bf16x8*)(Bs + r * 64 + cl * 16);
    }
#pragma unroll
    for (int mt = 0; mt < 4; ++mt)
#pragma unroll
      for (int nt = 0; nt < 4; ++nt)
        acc[mt][nt] = mfma32(af[mt], bfr[nt], acc[mt][nt]);
  }

#pragma unroll
  for (int mt = 0; mt < 4; ++mt)
#pragma unroll
    for (int nt = 0; nt < 4; ++nt)
#pragma unroll
      for (int r = 0; r < 4; ++r) {
        int m = m0 + wrow * 64 + mt * 16 + quad * 4 + r;
        int n = n0 + wcol * 64 + nt * 16 + l15;
        float v = acc[mt][nt][r];
        if (MODE == 0) {
          ((float*)Cout)[(size_t)m * 768 + n] = v;
        } else {
          int mat = n / 768, rem = n % 768;
          int h = rem >> 6, d = rem & 63;
          int b = m >> 11, s = m & 2047;
          ((bf16*)Cout)[(((size_t)(mat * 4 + b) * 12 + h) * 2048 + s) * 64 + d] = (bf16)v;
        }
      }
}

// ---------------- RoPE in-place on q,k: qkv[mat<2][b][h][s][64] ----
__global__ void rope_k(bf16* __restrict__ qk, const int* __restrict__ tpos,
                       const int* __restrict__ thetap) {
  int i = blockIdx.x * 256 + threadIdx.x; // < 2*4*12*2048*32 = 6291456
  int d2 = i & 31;
  int s = (i >> 5) & 2047;
  int rest = i >> 16;                     // (mat*4+b)*12 + h, 0..95
  int rb = rest / 12;                     // mat*4 + b
  int b = rb & 3;
  size_t off = ((size_t)rest * 2048 + s) * 64 + d2 * 2;
  int pos = tpos[b * 2048 + s];
  float lt = log2f((float)(*thetap));
  float fr = exp2f(-(float)d2 * (1.0f / 32.0f) * lt); // theta^(-2*d2/64)
  float ang = (float)pos * fr;
  float sn, cs;
  sincosf(ang, &sn, &cs);
  float te = (float)qk[off], to = (float)qk[off + 1];
  qk[off]     = (bf16)(te * cs - to * sn);
  qk[off + 1] = (bf16)(te * sn + to * cs);
}

// ---------------- V transpose: [bh][s][64] -> [bh][d][2048] --------
__global__ void vtrans(const bf16* __restrict__ v, bf16* __restrict__ vt) {
  __shared__ bf16 t[64][80];
  int bh = blockIdx.x >> 5, st = blockIdx.x & 31;
  int tid = threadIdx.x;
  const bf16* vin = v + (size_t)bh * 2048 * 64 + (size_t)st * 64 * 64;
#pragma unroll
  for (int i = 0; i < 2; ++i) {
    int L = i * 256 + tid;
    int sl = L >> 3, d0 = (L & 7) * 8;
    bf16x8 x = *(const bf16x8*)(vin + sl * 64 + d0);
#pragma unroll
    for (int j = 0; j < 8; ++j) t[d0 + j][sl] = x[j];
  }
  __syncthreads();
  bf16* vo = vt + (size_t)bh * 64 * 2048 + st * 64;
#pragma unroll
  for (int i = 0; i < 2; ++i) {
    int L = i * 256 + tid;
    int dl = L >> 3, s0 = (L & 7) * 8;
    bf16x8 y;
#pragma unroll
    for (int j = 0; j < 8; ++j) y[j] = t[dl][s0 + j];
    *(bf16x8*)(vo + (size_t)dl * 2048 + s0) = y;
  }
}

// ---------------- Flash attention (causal), 64 q/block -------------
// qkv: [mat][b][h][s][64] bf16 (q,k rope'd); vt: [b][h][d][2048]
// out: [b][s][768] bf16
__global__ void attn(const bf16* __restrict__ qkv, const bf16* __restrict__ vt,
                     bf16* __restrict__ aout) {
  const float SC = 0.125f * 1.44269504088896f; // 1/sqrt(64) * log2(e)
  const int qt = blockIdx.x, bh = blockIdx.y;
  const int b = bh / 12, h = bh % 12;
  const int tid = threadIdx.x, w = tid >> 6, lane = tid & 63;
  const int quad = lane >> 4, l15 = lane & 15;
  const bf16* Q  = qkv + (size_t)bh * (2048 * 64);
  const bf16* Kp = qkv + (size_t)(48 + bh) * (2048 * 64);
  const bf16* Vt = vt + (size_t)bh * (64 * 2048);
  __shared__ __align__(16) char Ks[64 * 128]; // 64 keys x 64 d, 8 chunks/row, swizzled
  __shared__ __align__(16) char Vs[64 * 128]; // 64 d x 64 keys, 8 chunks/row, swizzled

  const int qi = qt * 64 + w * 16 + l15; // this lane's softmax-layout query
  bf16x8 qf0 = *(const bf16x8*)(Q + (size_t)qi * 64 + quad * 8);
  bf16x8 qf1 = *(const bf16x8*)(Q + (size_t)qi * 64 + 32 + quad * 8);

  float mi = -1e30f, li = 0.f;
  f32x4 o[4];
#pragma unroll
  for (int dt = 0; dt < 4; ++dt) o[dt] = (f32x4){0.f, 0.f, 0.f, 0.f};

  for (int kb = 0; kb <= qt; ++kb) {
    __syncthreads();
#pragma unroll
    for (int i = 0; i < 2; ++i) {
      int L = i * 256 + tid;
      int r = L >> 3, cl = L & 7, cg = cl ^ (r & 7);
      gl_lds16(Kp + (size_t)(kb * 64 + r) * 64 + cg * 8, Ks + (i * 256 + w * 64) * 16);
      gl_lds16(Vt + (size_t)r * 2048 + kb * 64 + cg * 8, Vs + (i * 256 + w * 64) * 16);
    }
    __syncthreads();

    // S^T tiles: lane holds S^T[key=quad*4+rr][query=l15] per 16-key subblock
    float S[16];
#pragma unroll
    for (int sk = 0; sk < 4; ++sk) {
      int r = sk * 16 + l15;
      int cl0 = quad ^ (r & 7);
      int cl1 = (4 + quad) ^ (r & 7);
      bf16x8 kf0 = *(const bf16x8*)(Ks + r * 128 + cl0 * 16);
      bf16x8 kf1 = *(const bf16x8*)(Ks + r * 128 + cl1 * 16);
      f32x4 st = (f32x4){0.f, 0.f, 0.f, 0.f};
      st = mfma32(kf0, qf0, st);
      st = mfma32(kf1, qf1, st);
#pragma unroll
      for (int rr = 0; rr < 4; ++rr) S[sk * 4 + rr] = st[rr] * SC;
    }
    if (kb == qt) { // only the diagonal block needs masking
#pragma unroll
      for (int sk = 0; sk < 4; ++sk)
#pragma unroll
        for (int rr = 0; rr < 4; ++rr) {
          int key = kb * 64 + sk * 16 + quad * 4 + rr;
          if (key > qi) S[sk * 4 + rr] = -1e30f;
        }
    }

    float bm = S[0];
#pragma unroll
    for (int j = 1; j < 16; ++j) bm = fmaxf(bm, S[j]);
    bm = fmaxf(bm, __shfl_xor(bm, 16));
    bm = fmaxf(bm, __shfl_xor(bm, 32));
    float mn = fmaxf(mi, bm);
    float alpha = exp2f(mi - mn);
    float rs = 0.f;
#if HAVE_MFMA16
    s16x4 pf[4];
#endif
#pragma unroll
    for (int sk = 0; sk < 4; ++sk) {
      bf16x4 pb;
#pragma unroll
      for (int rr = 0; rr < 4; ++rr) {
        float p = exp2f(S[sk * 4 + rr] - mn);
        rs += p;
        S[sk * 4 + rr] = p;
        pb[rr] = (bf16)p;
      }
#if HAVE_MFMA16
      pf[sk] = __builtin_bit_cast(s16x4, pb);
#else
      (void)pb;
#endif
    }
    rs += __shfl_xor(rs, 16);
    rs += __shfl_xor(rs, 32);
    li = li * alpha + rs;
    mi = mn;

    float ar[4];
#pragma unroll
    for (int rr = 0; rr < 4; ++rr) ar[rr] = __shfl(alpha, quad * 4 + rr);
#pragma unroll
    for (int dt = 0; dt < 4; ++dt)
#pragma unroll
      for (int rr = 0; rr < 4; ++rr) o[dt][rr] *= ar[rr];

#if HAVE_MFMA16
    // P^T C/D layout == A-operand layout of 16x16x16: direct feed, no shuffle.
#pragma unroll
    for (int sk = 0; sk < 4; ++sk)
#pragma unroll
      for (int dt = 0; dt < 4; ++dt) {
        int rr = dt * 16 + l15;                 // Vt row (d)
        int c = sk * 2 + (quad >> 1);           // 16B chunk along keys
        int cl = c ^ (rr & 7);
        s16x4 vf = *(const s16x4*)(Vs + rr * 128 + cl * 16 + (quad & 1) * 8);
        o[dt] = mfma16(pf[sk], vf, o[dt]);
      }
#else
    // Fallback: assemble A-frags for 16x16x32 PV via shuffles (2 chunks of 32 keys)
#pragma unroll
    for (int kc = 0; kc < 2; ++kc) {
      bf16x8 af;
#pragma unroll
      for (int j = 0; j < 8; ++j) {
        int sq = (quad & 1) * 2 + (j >> 2);
        int src = sq * 16 + l15;
        float v0 = __shfl(S[kc * 8 + (j & 3)], src);
        float v1 = __shfl(S[kc * 8 + 4 + (j & 3)], src);
        af[j] = (bf16)((quad < 2) ? v0 : v1);
      }
#pragma unroll
      for (int dt = 0; dt < 4; ++dt) {
        int rr = dt * 16 + l15;
        int c = kc * 4 + quad;
        int cl = c ^ (rr & 7);
        bf16x8 vf = *(const bf16x8*)(Vs + rr * 128 + cl * 16);
        o[dt] = mfma32(af, vf, o[dt]);
      }
    }
#endif
  }

  float lr[4];
#pragma unroll
  for (int rr = 0; rr < 4; ++rr) lr[rr] = __shfl(li, quad * 4 + rr);
#pragma unroll
  for (int dt = 0; dt < 4; ++dt)
#pragma unroll
    for (int rr = 0; rr < 4; ++rr) {
      int q = qt * 64 + w * 16 + quad * 4 + rr;
      int n = h * 64 + dt * 16 + l15;
      aout[((size_t)b * 2048 + q) * 768 + n] = (bf16)(o[dt][rr] / lr[rr]);
    }
}

// ---------------- launch ----------------
extern "C" void kernel_launch(void* const* d_in, const int* in_sizes, int n_in,
                              void* d_out, int out_size, void* d_ws, size_t ws_size,
                              hipStream_t stream) {
  const float* x    = (const float*)d_in[0];
  const float* wqkv = (const float*)d_in[1];
  const float* wo   = (const float*)d_in[2];
  const int* tpos   = (const int*)d_in[3];
  const int* thetap = (const int*)d_in[5];

  char* ws = (char*)d_ws;
  // ws layout (bytes):
  bf16* xb    = (bf16*)(ws);              // 12,582,912  (reused as attn out)
  bf16* wqkvb = (bf16*)(ws + 12582912);   //  3,538,944
  bf16* wob   = (bf16*)(ws + 16121856);   //  1,179,648
  bf16* qkv   = (bf16*)(ws + 17301504);   // 37,748,736  [3][b][h][s][64]
  bf16* vtb   = (bf16*)(ws + 55050240);   // 12,582,912  [b][h][64][2048]
  bf16* vptr  = qkv + (size_t)2 * 4 * 12 * 2048 * 64;

  cvtk<<<6144, 256, 0, stream>>>(x, xb, 1572864);
  cvtk<<<1728, 256, 0, stream>>>(wqkv, wqkvb, 442368);
  cvtk<<<576, 256, 0, stream>>>(wo, wob, 147456);
  gemm_bt<1><<<dim3(64, 18), 256, 0, stream>>>(xb, wqkvb, (void*)qkv);
  rope_k<<<24576, 256, 0, stream>>>(qkv, tpos, thetap);
  vtrans<<<1536, 256, 0, stream>>>(vptr, vtb);
  attn<<<dim3(32, 48), 256, 0, stream>>>(qkv, vtb, xb);
  gemm_bt<0><<<dim3(64, 6), 256, 0, stream>>>(xb, wob, d_out);
}

// Round 2
// 250.373 us; speedup vs baseline: 1.1517x; 1.1517x over previous
//
#include <hip/hip_runtime.h>
#include <hip/hip_bf16.h>

// Problem dims (hardcoded): B=4, S=2048, D=768, H=12, hd=64
typedef __bf16 bf16;
typedef __bf16 bf16x8 __attribute__((ext_vector_type(8)));
typedef __bf16 bf16x4 __attribute__((ext_vector_type(4)));
typedef short  s16x4  __attribute__((ext_vector_type(4)));
typedef float  f32x4  __attribute__((ext_vector_type(4)));

#if defined(__has_builtin)
#if __has_builtin(__builtin_amdgcn_mfma_f32_16x16x16bf16_1k)
#define HAVE_MFMA16 1
#endif
#endif

__device__ __forceinline__ void gl_lds16(const void* g, void* l) {
  __builtin_amdgcn_global_load_lds(
      (__attribute__((address_space(1))) const void*)g,
      (__attribute__((address_space(3))) void*)l, 16, 0, 0);
}

__device__ __forceinline__ f32x4 mfma32(bf16x8 a, bf16x8 b, f32x4 c) {
  return __builtin_amdgcn_mfma_f32_16x16x32_bf16(a, b, c, 0, 0, 0);
}
#if HAVE_MFMA16
__device__ __forceinline__ f32x4 mfma16(s16x4 a, s16x4 b, f32x4 c) {
  return __builtin_amdgcn_mfma_f32_16x16x16bf16_1k(a, b, c, 0, 0, 0);
}
#endif

// ---------------- fp32 -> bf16 convert (vectorized) ----------------
__global__ void cvtk(const float* __restrict__ src, bf16* __restrict__ dst, int n4) {
  int i = blockIdx.x * 256 + threadIdx.x;
  if (i < n4) {
    float4 v = ((const float4*)src)[i];
    bf16x4 o;
    o[0] = (bf16)v.x; o[1] = (bf16)v.y; o[2] = (bf16)v.z; o[3] = (bf16)v.w;
    ((bf16x4*)dst)[i] = o;
  }
}

// ---------------- GEMM: C[M][N] = A[M][K] * B[N][K]^T, K=768 -------
// MODE 0: Cout = float*, row-major [M][768]
// MODE 1: Cout = bf16*, scatter to qkv[mat][b][h][s][64] (N=2304)
template <int MODE>
__global__ void gemm_bt(const bf16* __restrict__ A, const bf16* __restrict__ Bm,
                        void* __restrict__ Cout) {
  constexpr int K = 768;
  __shared__ __align__(16) char As[128 * 64]; // 128 rows x 32 bf16, 4 chunks/row, swizzled
  __shared__ __align__(16) char Bs[128 * 64];
  const int tid = threadIdx.x;
  const int w = tid >> 6, lane = tid & 63;
  const int quad = lane >> 4, l15 = lane & 15;
  const int wrow = w >> 1, wcol = w & 1;
  const int m0 = blockIdx.x * 128, n0 = blockIdx.y * 128;

  f32x4 acc[4][4];
#pragma unroll
  for (int mt = 0; mt < 4; ++mt)
#pragma unroll
    for (int nt = 0; nt < 4; ++nt) acc[mt][nt] = (f32x4){0.f, 0.f, 0.f, 0.f};

  for (int k0 = 0; k0 < K; k0 += 32) {
    __syncthreads();
#pragma unroll
    for (int i = 0; i < 2; ++i) {
      int L = i * 256 + tid;          // chunk index 0..511
      int r = L >> 2, cl = L & 3;
      int cg = cl ^ ((r >> 1) & 3);   // swizzle: conflict-free frag reads
      gl_lds16(A + (size_t)(m0 + r) * K + k0 + cg * 8, As + (i * 256 + w * 64) * 16);
      gl_lds16(Bm + (size_t)(n0 + r) * K + k0 + cg * 8, Bs + (i * 256 + w * 64) * 16);
    }
    __syncthreads();

    bf16x8 af[4], bfr[4];
#pragma unroll
    for (int mt = 0; mt < 4; ++mt) {
      int r = wrow * 64 + mt * 16 + l15;
      int cl = quad ^ ((r >> 1) & 3);
      af[mt] = *(const bf16x8*)(As + r * 64 + cl * 16);
    }
#pragma unroll
    for (int nt = 0; nt < 4; ++nt) {
      int r = wcol * 64 + nt * 16 + l15;
      int cl = quad ^ ((r >> 1) & 3);
      bfr[nt] = *(const bf16x8*)(Bs + r * 64 + cl * 16);
    }
#pragma unroll
    for (int mt = 0; mt < 4; ++mt)
#pragma unroll
      for (int nt = 0; nt < 4; ++nt)
        acc[mt][nt] = mfma32(af[mt], bfr[nt], acc[mt][nt]);
  }

#pragma unroll
  for (int mt = 0; mt < 4; ++mt)
#pragma unroll
    for (int nt = 0; nt < 4; ++nt)
#pragma unroll
      for (int r = 0; r < 4; ++r) {
        int m = m0 + wrow * 64 + mt * 16 + quad * 4 + r;
        int n = n0 + wcol * 64 + nt * 16 + l15;
        float v = acc[mt][nt][r];
        if (MODE == 0) {
          ((float*)Cout)[(size_t)m * 768 + n] = v;
        } else {
          int mat = n / 768, rem = n % 768;
          int h = rem >> 6, d = rem & 63;
          int b = m >> 11, s = m & 2047;
          ((bf16*)Cout)[(((size_t)(mat * 4 + b) * 12 + h) * 2048 + s) * 64 + d] = (bf16)v;
        }
      }
}

// ---------------- RoPE in-place on q,k: qkv[mat<2][b][h][s][64] ----
__global__ void rope_k(bf16* __restrict__ qk, const int* __restrict__ tpos,
                       const int* __restrict__ thetap) {
  int i = blockIdx.x * 256 + threadIdx.x; // < 2*4*12*2048*32 = 6291456
  int d2 = i & 31;
  int s = (i >> 5) & 2047;
  int rest = i >> 16;                     // (mat*4+b)*12 + h, 0..95
  int rb = rest / 12;                     // mat*4 + b
  int b = rb & 3;
  size_t off = ((size_t)rest * 2048 + s) * 64 + d2 * 2;
  int pos = tpos[b * 2048 + s];
  float lt = log2f((float)(*thetap));
  float fr = exp2f(-(float)d2 * (1.0f / 32.0f) * lt); // theta^(-2*d2/64)
  float ang = (float)pos * fr;
  float sn, cs;
  sincosf(ang, &sn, &cs);
  float te = (float)qk[off], to = (float)qk[off + 1];
  qk[off]     = (bf16)(te * cs - to * sn);
  qk[off + 1] = (bf16)(te * sn + to * cs);
}

// ---------------- V transpose: [bh][s][64] -> [bh][d][2048] --------
__global__ void vtrans(const bf16* __restrict__ v, bf16* __restrict__ vt) {
  __shared__ bf16 t[64][80];
  int bh = blockIdx.x >> 5, st = blockIdx.x & 31;
  int tid = threadIdx.x;
  const bf16* vin = v + (size_t)bh * 2048 * 64 + (size_t)st * 64 * 64;
#pragma unroll
  for (int i = 0; i < 2; ++i) {
    int L = i * 256 + tid;
    int sl = L >> 3, d0 = (L & 7) * 8;
    bf16x8 x = *(const bf16x8*)(vin + sl * 64 + d0);
#pragma unroll
    for (int j = 0; j < 8; ++j) t[d0 + j][sl] = x[j];
  }
  __syncthreads();
  bf16* vo = vt + (size_t)bh * 64 * 2048 + st * 64;
#pragma unroll
  for (int i = 0; i < 2; ++i) {
    int L = i * 256 + tid;
    int dl = L >> 3, s0 = (L & 7) * 8;
    bf16x8 y;
#pragma unroll
    for (int j = 0; j < 8; ++j) y[j] = t[dl][s0 + j];
    *(bf16x8*)(vo + (size_t)dl * 2048 + s0) = y;
  }
}

// ---------------- Flash attention (causal), 64 q/block -------------
// qkv: [mat][b][h][s][64] bf16 (q,k rope'd); vt: [b][h][d][2048]
// out: [b][s][768] bf16
// Pipelined: double-buffered K/V staging, one barrier per k-block;
// tile kb+1's global_load_lds issued before computing tile kb.
// Grid is 1D, longest blocks (qt=31) first to kill the causal tail.
__global__ void attn(const bf16* __restrict__ qkv, const bf16* __restrict__ vt,
                     bf16* __restrict__ aout) {
  const float SC = 0.125f * 1.44269504088896f; // 1/sqrt(64) * log2(e)
  const int bx = blockIdx.x;
  const int qt = 31 - (bx / 48);   // longest-first
  const int bh = bx % 48;
  const int b = bh / 12, h = bh % 12;
  const int tid = threadIdx.x, w = tid >> 6, lane = tid & 63;
  const int quad = lane >> 4, l15 = lane & 15;
  const bf16* Q  = qkv + (size_t)bh * (2048 * 64);
  const bf16* Kp = qkv + (size_t)(48 + bh) * (2048 * 64);
  const bf16* Vt = vt + (size_t)bh * (64 * 2048);
  __shared__ __align__(16) char Ks[2][64 * 128]; // 64 keys x 64 d, 8 chunks/row, swizzled
  __shared__ __align__(16) char Vs[2][64 * 128]; // 64 d x 64 keys, 8 chunks/row, swizzled

  const int qi = qt * 64 + w * 16 + l15; // this lane's softmax-layout query
  bf16x8 qf0 = *(const bf16x8*)(Q + (size_t)qi * 64 + quad * 8);
  bf16x8 qf1 = *(const bf16x8*)(Q + (size_t)qi * 64 + 32 + quad * 8);

  float mi = -1e30f, li = 0.f;
  f32x4 o[4];
#pragma unroll
  for (int dt = 0; dt < 4; ++dt) o[dt] = (f32x4){0.f, 0.f, 0.f, 0.f};

  // stage K/V tile kb into LDS buffer bufi (async; drained by next barrier)
  auto stage = [&](int kb, int bufi) {
#pragma unroll
    for (int i = 0; i < 2; ++i) {
      int L = i * 256 + tid;
      int r = L >> 3, cl = L & 7, cg = cl ^ (r & 7);
      gl_lds16(Kp + (size_t)(kb * 64 + r) * 64 + cg * 8, Ks[bufi] + (i * 256 + w * 64) * 16);
      gl_lds16(Vt + (size_t)r * 2048 + kb * 64 + cg * 8, Vs[bufi] + (i * 256 + w * 64) * 16);
    }
  };

  stage(0, 0);
  int buf = 0;

  for (int kb = 0; kb <= qt; ++kb) {
    __syncthreads();               // drains vmcnt: tile kb resident, buf^1 free
    if (kb < qt) stage(kb + 1, buf ^ 1);
    const char* Kb = Ks[buf];
    const char* Vb = Vs[buf];

    // S^T tiles: lane holds S^T[key=quad*4+rr][query=l15] per 16-key subblock
    float S[16];
#pragma unroll
    for (int sk = 0; sk < 4; ++sk) {
      int r = sk * 16 + l15;
      int cl0 = quad ^ (r & 7);
      int cl1 = (4 + quad) ^ (r & 7);
      bf16x8 kf0 = *(const bf16x8*)(Kb + r * 128 + cl0 * 16);
      bf16x8 kf1 = *(const bf16x8*)(Kb + r * 128 + cl1 * 16);
      f32x4 st = (f32x4){0.f, 0.f, 0.f, 0.f};
      st = mfma32(kf0, qf0, st);
      st = mfma32(kf1, qf1, st);
#pragma unroll
      for (int rr = 0; rr < 4; ++rr) S[sk * 4 + rr] = st[rr] * SC;
    }
    if (kb == qt) { // only the diagonal block needs masking
#pragma unroll
      for (int sk = 0; sk < 4; ++sk)
#pragma unroll
        for (int rr = 0; rr < 4; ++rr) {
          int key = kb * 64 + sk * 16 + quad * 4 + rr;
          if (key > qi) S[sk * 4 + rr] = -1e30f;
        }
    }

    float bm = S[0];
#pragma unroll
    for (int j = 1; j < 16; ++j) bm = fmaxf(bm, S[j]);
    bm = fmaxf(bm, __shfl_xor(bm, 16));
    bm = fmaxf(bm, __shfl_xor(bm, 32));
    float mn = fmaxf(mi, bm);
    float alpha = exp2f(mi - mn);
    float rs = 0.f;
#if HAVE_MFMA16
    s16x4 pf[4];
#endif
#pragma unroll
    for (int sk = 0; sk < 4; ++sk) {
      bf16x4 pb;
#pragma unroll
      for (int rr = 0; rr < 4; ++rr) {
        float p = exp2f(S[sk * 4 + rr] - mn);
        rs += p;
        S[sk * 4 + rr] = p;
        pb[rr] = (bf16)p;
      }
#if HAVE_MFMA16
      pf[sk] = __builtin_bit_cast(s16x4, pb);
#else
      (void)pb;
#endif
    }
    rs += __shfl_xor(rs, 16);
    rs += __shfl_xor(rs, 32);
    li = li * alpha + rs;
    mi = mn;

    float ar[4];
#pragma unroll
    for (int rr = 0; rr < 4; ++rr) ar[rr] = __shfl(alpha, quad * 4 + rr);
#pragma unroll
    for (int dt = 0; dt < 4; ++dt)
#pragma unroll
      for (int rr = 0; rr < 4; ++rr) o[dt][rr] *= ar[rr];

#if HAVE_MFMA16
    // P^T C/D layout == A-operand layout of 16x16x16: direct feed, no shuffle.
#pragma unroll
    for (int sk = 0; sk < 4; ++sk)
#pragma unroll
      for (int dt = 0; dt < 4; ++dt) {
        int rr = dt * 16 + l15;                 // Vt row (d)
        int c = sk * 2 + (quad >> 1);           // 16B chunk along keys
        int cl = c ^ (rr & 7);
        s16x4 vf = *(const s16x4*)(Vb + rr * 128 + cl * 16 + (quad & 1) * 8);
        o[dt] = mfma16(pf[sk], vf, o[dt]);
      }
#else
    // Fallback: assemble A-frags for 16x16x32 PV via shuffles (2 chunks of 32 keys)
#pragma unroll
    for (int kc = 0; kc < 2; ++kc) {
      bf16x8 af;
#pragma unroll
      for (int j = 0; j < 8; ++j) {
        int sq = (quad & 1) * 2 + (j >> 2);
        int src = sq * 16 + l15;
        float v0 = __shfl(S[kc * 8 + (j & 3)], src);
        float v1 = __shfl(S[kc * 8 + 4 + (j & 3)], src);
        af[j] = (bf16)((quad < 2) ? v0 : v1);
      }
#pragma unroll
      for (int dt = 0; dt < 4; ++dt) {
        int rr = dt * 16 + l15;
        int c = kc * 4 + quad;
        int cl = c ^ (rr & 7);
        bf16x8 vf = *(const bf16x8*)(Vb + rr * 128 + cl * 16);
        o[dt] = mfma32(af, vf, o[dt]);
      }
    }
#endif
    buf ^= 1;
  }

  float lr[4];
#pragma unroll
  for (int rr = 0; rr < 4; ++rr) lr[rr] = __shfl(li, quad * 4 + rr);
#pragma unroll
  for (int dt = 0; dt < 4; ++dt)
#pragma unroll
    for (int rr = 0; rr < 4; ++rr) {
      int q = qt * 64 + w * 16 + quad * 4 + rr;
      int n = h * 64 + dt * 16 + l15;
      aout[((size_t)b * 2048 + q) * 768 + n] = (bf16)(o[dt][rr] / lr[rr]);
    }
}

// ---------------- launch ----------------
extern "C" void kernel_launch(void* const* d_in, const int* in_sizes, int n_in,
                              void* d_out, int out_size, void* d_ws, size_t ws_size,
                              hipStream_t stream) {
  const float* x    = (const float*)d_in[0];
  const float* wqkv = (const float*)d_in[1];
  const float* wo   = (const float*)d_in[2];
  const int* tpos   = (const int*)d_in[3];
  const int* thetap = (const int*)d_in[5];

  char* ws = (char*)d_ws;
  // ws layout (bytes):
  bf16* xb    = (bf16*)(ws);              // 12,582,912  (reused as attn out)
  bf16* wqkvb = (bf16*)(ws + 12582912);   //  3,538,944
  bf16* wob   = (bf16*)(ws + 16121856);   //  1,179,648
  bf16* qkv   = (bf16*)(ws + 17301504);   // 37,748,736  [3][b][h][s][64]
  bf16* vtb   = (bf16*)(ws + 55050240);   // 12,582,912  [b][h][64][2048]
  bf16* vptr  = qkv + (size_t)2 * 4 * 12 * 2048 * 64;

  cvtk<<<6144, 256, 0, stream>>>(x, xb, 1572864);
  cvtk<<<1728, 256, 0, stream>>>(wqkv, wqkvb, 442368);
  cvtk<<<576, 256, 0, stream>>>(wo, wob, 147456);
  gemm_bt<1><<<dim3(64, 18), 256, 0, stream>>>(xb, wqkvb, (void*)qkv);
  rope_k<<<24576, 256, 0, stream>>>(qkv, tpos, thetap);
  vtrans<<<1536, 256, 0, stream>>>(vptr, vtb);
  attn<<<1536, 256, 0, stream>>>(qkv, vtb, xb);
  gemm_bt<0><<<dim3(64, 6), 256, 0, stream>>>(xb, wob, d_out);
}